// Round 5
// baseline (363.733 us; speedup 1.0000x reference)
//
#include <hip/hip_runtime.h>
#include <hip/hip_bf16.h>
#include <stdint.h>

// ---------------------------------------------------------------------------
// pcnn via MFMA, round 5: VALU diet + row-wave ILP restructure.
//  - Wave = one output row (5 waves/block, 320 thr). Per dy in {-1,0,1}:
//    read 7 slabs once (cols -1..5, dummy-zero for OOB), then 30 MFMAs into
//    10 independent acc chains (5 px x 2 M-tiles). 105 reads/block-layer.
//  - Epilogue uses hw v_cvt_pk_bf16_f32 (__float22bfloat162_rn).
//  - 3 blocks x 5 waves = 15 waves/CU; launch_bounds(320,4) caps VGPR 128.
// Mapping per conv layer, per output pixel p:
//    out[o, b] += sum_t W_t[25x25] @ H[c, nb(p,t), b]
// mfma_f32_16x16x32_bf16: N=16 patches, K=32 (25ch zero-pad), M=2x16 tiles.
// ---------------------------------------------------------------------------

typedef short bf16x8 __attribute__((ext_vector_type(8)));
typedef float f32x4  __attribute__((ext_vector_type(4)));

// d_ws layout: bf16 section (u16 elems):
//   WALL [7][9][32o][32c] @ 0      (64512)   layer0 + 6 mid, zero-padded
//   WL   [9][16o][32c]    @ 64512  (4608)    last layer (6 out ch used)
// f32 section @ byte 138240:
//   BALL [7][32] @0, BL [32] @224, WPOST [18][3][25] @256, BPOST [18] @1606
#define WSB_WL    64512
#define WSB_U16   69120
#define WSF_BYTE  138240
#define WSF_BALL  0
#define WSF_BL    224
#define WSF_WPOST 256
#define WSF_BPOST 1606
#define WSF_N     1624

#define NTHR 320   // 5 waves: wave w owns output row w

__device__ __forceinline__ float b2f(unsigned short u) {
  union { unsigned int u; float f; } v; v.u = ((unsigned int)u) << 16; return v.f;
}
__device__ __forceinline__ unsigned short f2b(float f) {
  union { float f; unsigned int u; } v; v.f = f;
  unsigned int r = v.u + 0x7fffu + ((v.u >> 16) & 1u);  // RNE
  return (unsigned short)(r >> 16);
}
// hw packed f32->bf16 RNE (gfx950 v_cvt_pk_bf16_f32 via HIP intrinsic)
__device__ __forceinline__ unsigned int pk2(float lo, float hi) {
  __hip_bfloat162 h = __float22bfloat162_rn(make_float2(lo, hi));
  union { __hip_bfloat162 h; unsigned int u; } v; v.h = h; return v.u;
}
__device__ __forceinline__ bool sniff_is_f32(const void* w0raw) {
  const unsigned short* q = (const unsigned short*)w0raw;
  int hits = 0;
  #pragma unroll
  for (int i = 0; i < 64; ++i) {
    unsigned int e = (q[i] >> 7) & 0xFFu;
    if (e >= 130u) ++hits;
  }
  return hits > 0;
}
__device__ __forceinline__ float ldw(const void* p, long idx, bool f32) {
  return f32 ? ((const float*)p)[idx] : b2f(((const unsigned short*)p)[idx]);
}

// ---------------- weight pre-pack (unchanged) ------------------------------
__global__ void prep_weights(const void* __restrict__ w0,
                             const void* __restrict__ b0,
                             const void* __restrict__ wm,
                             const void* __restrict__ bm,
                             const void* __restrict__ wl,
                             const void* __restrict__ bl,
                             const void* __restrict__ wp,
                             const void* __restrict__ bp,
                             unsigned short* __restrict__ wsb,
                             float* __restrict__ wsf) {
  const bool f32 = sniff_is_f32(w0);
  int e = blockIdx.x * blockDim.x + threadIdx.x;
  if (e < WSB_WL) {                       // WALL[l][t][o][c]
    int l = e / 9216, r = e % 9216, t = r / 1024, r2 = r % 1024;
    int o = r2 / 32, c = r2 % 32;
    float v = 0.f;
    if (l == 0) { if (o < 25 && c < 8)  v = ldw(w0, (o * 8 + c) * 9 + t, f32); }
    else        { if (o < 25 && c < 25) v = ldw(wm, (((l - 1) * 25 + o) * 25 + c) * 9 + t, f32); }
    wsb[e] = f2b(v);
  } else if (e < WSB_U16) {               // WL[t][o][c]
    int q = e - WSB_WL;
    int t = q / 512, r = q % 512, o = r / 32, c = r % 32;
    float v = 0.f;
    if (o < 6 && c < 25) v = ldw(wl, (o * 25 + c) * 9 + t, f32);
    wsb[e] = f2b(v);
  } else {
    int q = e - WSB_U16;
    if (q < 224) {                        // BALL[l][32]
      int l = q / 32, o = q % 32;
      float v = 0.f;
      if (o < 25) v = (l == 0) ? ldw(b0, o, f32) : ldw(bm, (l - 1) * 25 + o, f32);
      wsf[WSF_BALL + q] = v;
    } else if (q < 256) {
      int o = q - 224;
      wsf[WSF_BL + o] = (o < 6) ? ldw(bl, o, f32) : 0.f;
    } else if (q < 256 + 1350) {
      wsf[WSF_WPOST + (q - 256)] = ldw(wp, q - 256, f32);
    } else if (q < 256 + 1350 + 18) {
      wsf[WSF_BPOST + (q - 1606)] = ldw(bp, q - 1606, f32);
    }
  }
}

// ---------------- one conv layer, one output row per wave ------------------
__device__ __forceinline__ void conv_row(
    const short* __restrict__ hin, short* __restrict__ hout,
    const short* __restrict__ dzero,
    const unsigned short* __restrict__ WA, const float* __restrict__ biasv,
    int row, int col, int quad) {
  const f32x4 bias0 = *(const f32x4*)(biasv + quad * 4);
  const f32x4 bias1 = *(const f32x4*)(biasv + 16 + quad * 4);
  const int loffs = col * 32 + quad * 8;  // shorts, within a 512-short slab

  f32x4 a0[5], a1[5];
  #pragma unroll
  for (int px = 0; px < 5; ++px) { a0[px] = bias0; a1[px] = bias1; }

  #pragma unroll 1
  for (int dy = 0; dy < 3; ++dy) {
    const int ny = row + dy - 1;
    const bool rv = (unsigned)ny < 5u;
    // read the 7 slabs (cols -1..5) once; OOB -> zero dummy slab
    bf16x8 s[7];
    #pragma unroll
    for (int j = 0; j < 7; ++j) {
      const int nx = j - 1;
      const bool v = rv & ((unsigned)nx < 5u);
      const short* bp = v ? hin + (ny * 5 + nx) * 512 : dzero;
      s[j] = *(const bf16x8*)(bp + loffs);
    }
    // A-fragments for this dy's 3 taps x 2 M-tiles
    #pragma unroll
    for (int dx = 0; dx < 3; ++dx) {
      const int t = dy * 3 + dx;
      const bf16x8 af0 = *(const bf16x8*)(WA + (t * 32 + col) * 32 + quad * 8);
      const bf16x8 af1 = *(const bf16x8*)(WA + (t * 32 + 16 + col) * 32 + quad * 8);
      #pragma unroll
      for (int px = 0; px < 5; ++px) {
        a0[px] = __builtin_amdgcn_mfma_f32_16x16x32_bf16(af0, s[px + dx], a0[px], 0, 0, 0);
        a1[px] = __builtin_amdgcn_mfma_f32_16x16x32_bf16(af1, s[px + dx], a1[px], 0, 0, 0);
      }
    }
  }

  // epilogue: relu + hw pack + store
  #pragma unroll
  for (int px = 0; px < 5; ++px) {
    short* op = hout + (row * 5 + px) * 512 + col * 32;
    uint2 s0;
    s0.x = pk2(fmaxf(a0[px][0], 0.f), fmaxf(a0[px][1], 0.f));
    s0.y = pk2(fmaxf(a0[px][2], 0.f), fmaxf(a0[px][3], 0.f));
    *(uint2*)(op + quad * 4) = s0;
    if (quad < 2) {
      uint2 s1;
      s1.x = pk2(fmaxf(a1[px][0], 0.f), fmaxf(a1[px][1], 0.f));
      s1.y = pk2(fmaxf(a1[px][2], 0.f), fmaxf(a1[px][3], 0.f));
      *(uint2*)(op + 16 + quad * 4) = s1;
    } else if (quad == 2) {  // ch 24
      *(unsigned short*)(op + 24) = f2b(fmaxf(a1[px][0], 0.f));
    }
  }
}

// ---------------- main kernel ----------------------------------------------
__global__ __launch_bounds__(NTHR, 4) void pcnn_mfma(
    const void* __restrict__ inp,
    const void* __restrict__ w0raw,
    const unsigned short* __restrict__ wsb,
    const float* __restrict__ wsf,
    void* __restrict__ out) {
  __shared__ __align__(16) short Ha[25 * 512];   // [25pix][16b][32ch] 25600 B
  __shared__ __align__(16) short Hb[25 * 512];   // 25600 B
  __shared__ __align__(16) short Hz[512];        // zero dummy slab 1024 B
  __shared__ float colb[16 * 18];                // colors 1152 B
  // overlays on dead Ha after the mid layers:
  float* logits = (float*)Ha;                    // [25p][16b][8] f32 12800 B
  float* smb    = (float*)(Ha + 6400);           // [25p][16b][6] f32  9600 B

  const bool f32m = sniff_is_f32(w0raw);
  const int tid  = threadIdx.x;
  const int lane = tid & 63;
  const int row  = tid >> 6;             // wave w -> output row w (0..4)
  const int col  = lane & 15;            // MFMA n (patch) / m (out ch)
  const int quad = lane >> 4;            // MFMA k-block / row-block
  const int g    = blockIdx.x;           // group of 16 patches

  // zero Ha, Hb (ch 25..31 pad must stay 0), dummy slab
  for (int i = tid; i < 6400; i += NTHR) ((unsigned int*)Ha)[i] = 0u;
  for (int i = tid; i < 6400; i += NTHR) ((unsigned int*)Hb)[i] = 0u;
  if (tid < 256) ((unsigned int*)Hz)[tid] = 0u;
  __syncthreads();

  // stage input: [b][8c][25pix] -> Ha[pix][b][c]
  for (int e = tid; e < 3200; e += NTHR) {
    int b = e / 200, r = e % 200, c = r / 25, pix = r % 25;
    float v = ldw(inp, (long)g * 3200 + e, f32m);
    ((unsigned short*)Ha)[(pix * 16 + b) * 32 + c] = f2b(v);
  }
  __syncthreads();

  // ---- 7 relu conv layers, compile-time ping-pong Ha<->Hb ----
  conv_row(Ha, Hb, Hz, wsb + 0 * 9216, wsf + WSF_BALL + 0 * 32, row, col, quad);
  __syncthreads();
  #pragma unroll
  for (int lp = 1; lp < 6; lp += 2) {
    conv_row(Hb, Ha, Hz, wsb + lp * 9216, wsf + WSF_BALL + lp * 32, row, col, quad);
    __syncthreads();
    conv_row(Ha, Hb, Hz, wsb + (lp + 1) * 9216, wsf + WSF_BALL + (lp + 1) * 32, row, col, quad);
    __syncthreads();
  }
  // final hidden in Hb; Ha dead -> logits overlay.

  // ---- last layer: 25 -> 6 logits (no relu), row-wise, single M-tile ----
  {
    const unsigned short* WA = wsb + WSB_WL;
    const f32x4 biasl = *(const f32x4*)(wsf + WSF_BL + quad * 4);
    const int loffs = col * 32 + quad * 8;
    f32x4 al[5];
    #pragma unroll
    for (int px = 0; px < 5; ++px) al[px] = biasl;

    #pragma unroll 1
    for (int dy = 0; dy < 3; ++dy) {
      const int ny = row + dy - 1;
      const bool rv = (unsigned)ny < 5u;
      bf16x8 s[7];
      #pragma unroll
      for (int j = 0; j < 7; ++j) {
        const int nx = j - 1;
        const bool v = rv & ((unsigned)nx < 5u);
        const short* bp = v ? Hb + (ny * 5 + nx) * 512 : Hz;
        s[j] = *(const bf16x8*)(bp + loffs);
      }
      #pragma unroll
      for (int dx = 0; dx < 3; ++dx) {
        const int t = dy * 3 + dx;
        const bf16x8 afl = *(const bf16x8*)(WA + (t * 16 + col) * 32 + quad * 8);
        #pragma unroll
        for (int px = 0; px < 5; ++px)
          al[px] = __builtin_amdgcn_mfma_f32_16x16x32_bf16(afl, s[px + dx], al[px], 0, 0, 0);
      }
    }
    #pragma unroll
    for (int px = 0; px < 5; ++px) {
      float* lp = logits + ((row * 5 + px) * 16 + col) * 8;
      if (quad == 0)      { *(f32x4*)lp = al[px]; }                // rows 0..3
      else if (quad == 1) { lp[4] = al[px][0]; lp[5] = al[px][1]; } // rows 4,5
    }
  }
  __syncthreads();

  // ---- epilogue: colors (postconv, re-read input from global) + softmax ----
  {
    const float* WP = wsf + WSF_WPOST;
    const float* BP = wsf + WSF_BPOST;
    for (int j = tid; j < 288; j += NTHR) {
      int b = j / 18, oc = j % 18;
      const long ib = (long)g * 3200 + b * 200;
      float s = BP[oc];
      #pragma unroll
      for (int ic = 0; ic < 3; ++ic) {
        #pragma unroll
        for (int pix = 0; pix < 25; ++pix)
          s = fmaf(WP[(oc * 3 + ic) * 25 + pix], ldw(inp, ib + ic * 25 + pix, f32m), s);
      }
      colb[b * 18 + oc] = s;
    }
    for (int j = tid; j < 400; j += NTHR) {
      const float* lp = logits + j * 8;
      float m = lp[0];
      #pragma unroll
      for (int k = 1; k < 6; ++k) m = fmaxf(m, lp[k]);
      float e[6], s = 0.f;
      #pragma unroll
      for (int k = 0; k < 6; ++k) { e[k] = __expf(lp[k] - m); s += e[k]; }
      const float inv = 1.f / s;
      #pragma unroll
      for (int k = 0; k < 6; ++k) smb[j * 6 + k] = e[k] * inv;
    }
  }
  __syncthreads();

  // ---- mix + store: out[b][c][p] = sum_w colors[b][c*6+w] * sm[p][b][w] ----
  for (int e = tid; e < 1200; e += NTHR) {
    int b = e / 75, r = e % 75, c = r / 25, p = r % 25;
    float v = 0.f;
    #pragma unroll
    for (int w = 0; w < 6; ++w)
      v = fmaf(colb[b * 18 + c * 6 + w], smb[(p * 16 + b) * 6 + w], v);
    const long oidx = (long)g * 1200 + e;
    if (f32m) ((float*)out)[oidx] = v;
    else      ((unsigned short*)out)[oidx] = f2b(v);
  }
}

extern "C" void kernel_launch(void* const* d_in, const int* in_sizes, int n_in,
                              void* d_out, int out_size, void* d_ws, size_t ws_size,
                              hipStream_t stream) {
  unsigned short* wsb = (unsigned short*)d_ws;
  float* wsf = (float*)((char*)d_ws + WSF_BYTE);
  const int B = in_sizes[0] / 200;  // 32768

  const int prep_n = WSB_U16 + WSF_N;
  prep_weights<<<(prep_n + 255) / 256, 256, 0, stream>>>(
      d_in[1], d_in[2], d_in[3], d_in[4], d_in[5], d_in[6], d_in[7], d_in[8],
      wsb, wsf);
  pcnn_mfma<<<B / 16, NTHR, 0, stream>>>(d_in[0], d_in[1], wsb, wsf, d_out);
}

// Round 6
// 287.118 us; speedup vs baseline: 1.2668x; 1.2668x over previous
//
#include <hip/hip_runtime.h>
#include <hip/hip_bf16.h>
#include <stdint.h>

// ---------------------------------------------------------------------------
// pcnn round 6: 32x32x16 MFMA scatter (row-stationary) formulation.
//  - Block = 32 patches, 5 waves (320 thr); wave r owns output row r with
//    5 persistent f32x16 accumulators (M=32 = all 25 out-ch in one tile).
//  - Scatter: per q-row, each input pixel's B-frag is read ONCE (2 K-steps)
//    and fed to the 1..3 output pixels that consume it -> 130 b128 reads and
//    338 MFMAs per block-layer (no padded taps, no dummy slab).
//  - In-place H: compute(reads) | barrier | relu-store | barrier.
//  - Chunk-XOR swizzle (chunk ^ (b&3)) -> conflict-free reads, ~8-way stores.
//  - Logits: same GEMM; softmax in-register (shfl_xor 32); sm overlays dead H.
// ---------------------------------------------------------------------------

typedef short bf16x8 __attribute__((ext_vector_type(8)));
typedef float f32x4  __attribute__((ext_vector_type(4)));
typedef float f32x16 __attribute__((ext_vector_type(16)));

#define NTHR 320

// d_ws: WALL bf16 [8 gemm layers][9 taps][32 o][32 c] @0  (73728 u16)
//   l=0: conv0 (c<8), l=1..6: mid, l=7: last (o<6)
// f32 @ byte 147456: BALL[8][32] @0, WPOST[18][3][25] @256, BPOST[18] @1606
#define WSB_N     73728
#define WSF_BYTE  147456
#define WSF_BALL  0
#define WSF_WPOST 256
#define WSF_BPOST 1606
#define WSF_N     1624

__device__ __forceinline__ float b2f(unsigned short u) {
  union { unsigned int u; float f; } v; v.u = ((unsigned int)u) << 16; return v.f;
}
__device__ __forceinline__ unsigned short f2b(float f) {
  union { float f; unsigned int u; } v; v.f = f;
  unsigned int r = v.u + 0x7fffu + ((v.u >> 16) & 1u);  // RNE
  return (unsigned short)(r >> 16);
}
__device__ __forceinline__ unsigned int pk2(float lo, float hi) {
  __hip_bfloat162 h = __float22bfloat162_rn(make_float2(lo, hi));
  union { __hip_bfloat162 h; unsigned int u; } v; v.h = h; return v.u;
}
__device__ __forceinline__ bool sniff_is_f32(const void* w0raw) {
  const unsigned short* q = (const unsigned short*)w0raw;
  int hits = 0;
  #pragma unroll
  for (int i = 0; i < 64; ++i) {
    unsigned int e = (q[i] >> 7) & 0xFFu;
    if (e >= 130u) ++hits;
  }
  return hits > 0;
}
__device__ __forceinline__ float ldw(const void* p, long idx, bool f32) {
  return f32 ? ((const float*)p)[idx] : b2f(((const unsigned short*)p)[idx]);
}

// ---------------- weight pre-pack ------------------------------------------
__global__ void prep_weights(const void* __restrict__ w0,
                             const void* __restrict__ b0,
                             const void* __restrict__ wm,
                             const void* __restrict__ bm,
                             const void* __restrict__ wl,
                             const void* __restrict__ bl,
                             const void* __restrict__ wp,
                             const void* __restrict__ bp,
                             unsigned short* __restrict__ wsb,
                             float* __restrict__ wsf) {
  const bool f32 = sniff_is_f32(w0);
  int e = blockIdx.x * blockDim.x + threadIdx.x;
  if (e < WSB_N) {                        // WALL[l][t][o32][c32]
    int l = e / 9216, r = e % 9216, t = r / 1024, r2 = r % 1024;
    int o = r2 >> 5, c = r2 & 31;
    float v = 0.f;
    if (l == 0)     { if (o < 25 && c < 8)  v = ldw(w0, (o * 8 + c) * 9 + t, f32); }
    else if (l < 7) { if (o < 25 && c < 25) v = ldw(wm, (((l - 1) * 25 + o) * 25 + c) * 9 + t, f32); }
    else            { if (o < 6  && c < 25) v = ldw(wl, (o * 25 + c) * 9 + t, f32); }
    wsb[e] = f2b(v);
  } else {
    int q = e - WSB_N;
    if (q < 256) {                        // BALL[l][32]
      int l = q >> 5, row = q & 31;
      float v = 0.f;
      if (l == 0)     { if (row < 25) v = ldw(b0, row, f32); }
      else if (l < 7) { if (row < 25) v = ldw(bm, (l - 1) * 25 + row, f32); }
      else            { if (row < 6)  v = ldw(bl, row, f32); }
      wsf[WSF_BALL + q] = v;
    } else if (q < 256 + 1350) {
      wsf[WSF_WPOST + (q - 256)] = ldw(wp, q - 256, f32);
    } else if (q < WSF_N) {
      wsf[WSF_BPOST + (q - 1606)] = ldw(bp, q - 1606, f32);
    }
  }
}

// ---------------- one GEMM pass (conv or logits) ---------------------------
// H layout: [25 px][32 b][32 ch] bf16, 16B chunks swizzled: chunk' = chunk^(b&3)
// A/B frag lane map (32x32x16): m|n = lane&31, k = (lane>>5)*8 + j
// C/D lane map: col(n) = lane&31, row(m) = (reg&3) + 8*(reg>>2) + 4*(lane>>5)
__device__ __forceinline__ void gemm_pass(
    unsigned char* __restrict__ H, const unsigned short* __restrict__ wsb,
    const float* __restrict__ wsf, float* __restrict__ smb,
    int l, int nsteps, bool logits,
    int r, int b, int half, int swz) {
  f32x16 acc[5];
  {
    f32x4 bv[4];
    #pragma unroll
    for (int gq = 0; gq < 4; ++gq)
      bv[gq] = *(const f32x4*)(wsf + WSF_BALL + l * 32 + gq * 8 + half * 4);
    #pragma unroll
    for (int j = 0; j < 5; ++j)
      #pragma unroll
      for (int gq = 0; gq < 4; ++gq)
        #pragma unroll
        for (int q = 0; q < 4; ++q)
          acc[j][gq * 4 + q] = bv[gq][q];
  }
  const unsigned short* WL = wsb + l * 9216;

  #pragma unroll
  for (int dy = 0; dy < 3; ++dy) {
    const int ny = r + dy - 1;
    if ((unsigned)ny < 5u) {             // wave-uniform branch
      bf16x8 af[3][2];
      #pragma unroll
      for (int dx = 0; dx < 3; ++dx)
        #pragma unroll
        for (int s = 0; s < 2; ++s)
          if (s < nsteps)
            af[dx][s] = *(const bf16x8*)(WL + (dy * 3 + dx) * 1024 + b * 32 + s * 16 + half * 8);
      #pragma unroll
      for (int nx = 0; nx < 5; ++nx) {
        const int q = ny * 5 + nx;
        #pragma unroll
        for (int s = 0; s < 2; ++s) {
          if (s < nsteps) {
            bf16x8 bf = *(const bf16x8*)(H + q * 2048 + b * 64 + (((s * 2 + half) ^ swz) << 4));
            #pragma unroll
            for (int dx = 0; dx < 3; ++dx) {
              const int j = nx - dx + 1;   // output px consuming input nx via tap dx
              if (j >= 0 && j < 5)
                acc[j] = __builtin_amdgcn_mfma_f32_32x32x16_bf16(af[dx][s], bf, acc[j], 0, 0, 0);
            }
          }
        }
      }
    }
  }
  __syncthreads();   // all H reads complete before in-place overwrite / overlay

  if (!logits) {
    // relu + pack + in-place store. reg group gq (regs 4gq..4gq+3) = rows
    // 8*gq + 4*half + 0..3 ; group 3 partial (row 24 only, half 0).
    #pragma unroll
    for (int j = 0; j < 5; ++j) {
      unsigned char* base = H + (r * 5 + j) * 2048 + b * 64;
      #pragma unroll
      for (int gq = 0; gq < 3; ++gq) {
        const int ch0 = gq * 8 + half * 4;
        uint2 sv;
        sv.x = pk2(fmaxf(acc[j][gq * 4 + 0], 0.f), fmaxf(acc[j][gq * 4 + 1], 0.f));
        sv.y = pk2(fmaxf(acc[j][gq * 4 + 2], 0.f), fmaxf(acc[j][gq * 4 + 3], 0.f));
        *(uint2*)(base + (((ch0 >> 3) ^ swz) << 4) + (ch0 & 7) * 2) = sv;
      }
      if (half == 0)  // row 24 = acc reg 12
        *(unsigned short*)(base + ((3 ^ swz) << 4)) = f2b(fmaxf(acc[j][12], 0.f));
    }
    __syncthreads();
  } else {
    // logits rows 0..5: half0 has rows 0-3 (regs 0-3); rows 4,5 live in
    // half1 regs 0,1 -> pull via shfl_xor(32). Softmax -> smb (overlays H).
    #pragma unroll
    for (int j = 0; j < 5; ++j) {
      const int px = r * 5 + j;
      float l4 = __shfl_xor(acc[j][0], 32);
      float l5 = __shfl_xor(acc[j][1], 32);
      if (half == 0) {
        float v0 = acc[j][0], v1 = acc[j][1], v2 = acc[j][2], v3 = acc[j][3];
        float m = fmaxf(fmaxf(fmaxf(v0, v1), fmaxf(v2, v3)), fmaxf(l4, l5));
        float e0 = __expf(v0 - m), e1 = __expf(v1 - m), e2 = __expf(v2 - m);
        float e3 = __expf(v3 - m), e4 = __expf(l4 - m), e5 = __expf(l5 - m);
        float inv = 1.f / (e0 + e1 + e2 + e3 + e4 + e5);
        float* sp = smb + (px * 32 + b) * 6;
        sp[0] = e0 * inv; sp[1] = e1 * inv; sp[2] = e2 * inv;
        sp[3] = e3 * inv; sp[4] = e4 * inv; sp[5] = e5 * inv;
      }
    }
    __syncthreads();
  }
}

// ---------------- main kernel ----------------------------------------------
__global__ __launch_bounds__(NTHR, 3) void pcnn_mfma(
    const void* __restrict__ inp,
    const void* __restrict__ w0raw,
    const unsigned short* __restrict__ wsb,
    const float* __restrict__ wsf,
    void* __restrict__ out) {
  __shared__ __align__(16) unsigned char H[25 * 2048];  // 51200 B
  __shared__ float colb[32 * 18];                       // colors
  float* smb = (float*)H;                               // [25][32][6] overlay

  const bool f32m = sniff_is_f32(w0raw);
  const int tid  = threadIdx.x;
  const int lane = tid & 63;
  const int r    = tid >> 6;        // wave = output row
  const int b    = lane & 31;       // patch column (n) / out-ch row (m)
  const int half = lane >> 5;
  const int swz  = b & 3;
  const int g    = blockIdx.x;      // group of 32 patches

  // zero H (ch 25..31 pad must stay zero through all layers)
  for (int i = tid; i < 12800; i += NTHR) ((unsigned int*)H)[i] = 0u;
  __syncthreads();
  // stage input [b][8c][25pix] -> H[pix][b][c] (c<8: logical chunk 0)
  for (int e = tid; e < 6400; e += NTHR) {
    int pb = e / 200, rr = e % 200, c = rr / 25, pix = rr % 25;
    float v = ldw(inp, (long)g * 6400 + e, f32m);
    *(unsigned short*)(H + pix * 2048 + pb * 64 + ((pb & 3) << 4) + c * 2) = f2b(v);
  }
  __syncthreads();

  // ---- 7 relu conv layers + logits layer ----
  gemm_pass(H, wsb, wsf, smb, 0, 1, false, r, b, half, swz);
  #pragma unroll 1
  for (int l = 1; l < 7; ++l)
    gemm_pass(H, wsb, wsf, smb, l, 2, false, r, b, half, swz);
  gemm_pass(H, wsb, wsf, smb, 7, 2, true, r, b, half, swz);

  // ---- colors: 5x5 VALID conv on first 3 input channels (global re-read) ----
  for (int j = tid; j < 576; j += NTHR) {
    int pb = j / 18, oc = j % 18;
    const long ib = (long)g * 6400 + pb * 200;
    float s = wsf[WSF_BPOST + oc];
    #pragma unroll
    for (int ic = 0; ic < 3; ++ic)
      #pragma unroll
      for (int pix = 0; pix < 25; ++pix)
        s = fmaf(wsf[WSF_WPOST + (oc * 3 + ic) * 25 + pix],
                 ldw(inp, ib + ic * 25 + pix, f32m), s);
    colb[pb * 18 + oc] = s;
  }
  __syncthreads();

  // ---- mix + store: out[b][c][p] = sum_w colors[b][c*6+w] * sm[p][b][w] ----
  for (int e = tid; e < 2400; e += NTHR) {
    int pb = e / 75, rr = e % 75, c = rr / 25, p = rr % 25;
    float v = 0.f;
    #pragma unroll
    for (int w = 0; w < 6; ++w)
      v = fmaf(colb[pb * 18 + c * 6 + w], smb[(p * 32 + pb) * 6 + w], v);
    const long oidx = (long)g * 2400 + e;
    if (f32m) ((float*)out)[oidx] = v;
    else      ((unsigned short*)out)[oidx] = f2b(v);
  }
}

extern "C" void kernel_launch(void* const* d_in, const int* in_sizes, int n_in,
                              void* d_out, int out_size, void* d_ws, size_t ws_size,
                              hipStream_t stream) {
  unsigned short* wsb = (unsigned short*)d_ws;
  float* wsf = (float*)((char*)d_ws + WSF_BYTE);
  const int B = in_sizes[0] / 200;  // 32768

  const int prep_n = WSB_N + WSF_N;  // 75352
  prep_weights<<<(prep_n + 255) / 256, 256, 0, stream>>>(
      d_in[1], d_in[2], d_in[3], d_in[4], d_in[5], d_in[6], d_in[7], d_in[8],
      wsb, wsf);
  pcnn_mfma<<<B / 32, NTHR, 0, stream>>>(d_in[0], d_in[1], wsb, wsf, d_out);
}

// Round 7
// 285.015 us; speedup vs baseline: 1.2762x; 1.0074x over previous
//
#include <hip/hip_runtime.h>
#include <hip/hip_bf16.h>
#include <stdint.h>

// ---------------------------------------------------------------------------
// pcnn round 7: bank-conflict-free chunk-major LDS + LDS-staged weights.
//  - H[px25][chunk4][b32][16B]: B-frag read = contiguous 512B/half-wave ->
//    all-32-banks bandwidth floor (R6's b*64 stride used only 16 banks).
//  - Weights for the current layer live in LDS Wbuf (18.4 KB). Next layer's
//    weights are prefetched to VGPRs at the top of the write phase and
//    ds-written before the closing barrier -> compute phase has ZERO global
//    loads; A-frags are pipelined ds_read_b128.
//  - Same 32x32x16 row-stationary scatter as R6 (verified correct).
// ---------------------------------------------------------------------------

typedef short bf16x8 __attribute__((ext_vector_type(8)));
typedef float f32x4  __attribute__((ext_vector_type(4)));
typedef float f32x16 __attribute__((ext_vector_type(16)));

#define NTHR 320

// d_ws: WALL bf16 [8 layers][9 taps][chunk4][o32][c8] @0 (73728 u16; 1152
//   uint4 per layer). l=0: conv0 (c<8), l=1..6: mid, l=7: last (o<6).
// f32 @ byte 147456: BALL[8][32] @0, WPOST[18][3][25] @256, BPOST[18] @1606
#define WSB_N     73728
#define WSF_BYTE  147456
#define WSF_BALL  0
#define WSF_WPOST 256
#define WSF_BPOST 1606
#define WSF_N     1624

__device__ __forceinline__ float b2f(unsigned short u) {
  union { unsigned int u; float f; } v; v.u = ((unsigned int)u) << 16; return v.f;
}
__device__ __forceinline__ unsigned short f2b(float f) {
  union { float f; unsigned int u; } v; v.f = f;
  unsigned int r = v.u + 0x7fffu + ((v.u >> 16) & 1u);  // RNE
  return (unsigned short)(r >> 16);
}
__device__ __forceinline__ unsigned int pk2(float lo, float hi) {
  __hip_bfloat162 h = __float22bfloat162_rn(make_float2(lo, hi));
  union { __hip_bfloat162 h; unsigned int u; } v; v.h = h; return v.u;
}
__device__ __forceinline__ bool sniff_is_f32(const void* w0raw) {
  const unsigned short* q = (const unsigned short*)w0raw;
  int hits = 0;
  #pragma unroll
  for (int i = 0; i < 64; ++i) {
    unsigned int e = (q[i] >> 7) & 0xFFu;
    if (e >= 130u) ++hits;
  }
  return hits > 0;
}
__device__ __forceinline__ float ldw(const void* p, long idx, bool f32) {
  return f32 ? ((const float*)p)[idx] : b2f(((const unsigned short*)p)[idx]);
}

// ---------------- weight pre-pack ------------------------------------------
__global__ void prep_weights(const void* __restrict__ w0,
                             const void* __restrict__ b0,
                             const void* __restrict__ wm,
                             const void* __restrict__ bm,
                             const void* __restrict__ wl,
                             const void* __restrict__ bl,
                             const void* __restrict__ wp,
                             const void* __restrict__ bp,
                             unsigned short* __restrict__ wsb,
                             float* __restrict__ wsf) {
  const bool f32 = sniff_is_f32(w0);
  int e = blockIdx.x * blockDim.x + threadIdx.x;
  if (e < WSB_N) {                        // WALL[l][t][chunk][o][c8]
    int l = e / 9216, r = e % 9216, t = r / 1024, r2 = r % 1024;
    int chunk = r2 >> 8, o = (r2 >> 3) & 31, cc = r2 & 7;
    int c = chunk * 8 + cc;
    float v = 0.f;
    if (l == 0)     { if (o < 25 && c < 8)  v = ldw(w0, (o * 8 + c) * 9 + t, f32); }
    else if (l < 7) { if (o < 25 && c < 25) v = ldw(wm, (((l - 1) * 25 + o) * 25 + c) * 9 + t, f32); }
    else            { if (o < 6  && c < 25) v = ldw(wl, (o * 25 + c) * 9 + t, f32); }
    wsb[e] = f2b(v);
  } else {
    int q = e - WSB_N;
    if (q < 256) {                        // BALL[l][32]
      int l = q >> 5, row = q & 31;
      float v = 0.f;
      if (l == 0)     { if (row < 25) v = ldw(b0, row, f32); }
      else if (l < 7) { if (row < 25) v = ldw(bm, (l - 1) * 25 + row, f32); }
      else            { if (row < 6)  v = ldw(bl, row, f32); }
      wsf[WSF_BALL + q] = v;
    } else if (q < 256 + 1350) {
      wsf[WSF_WPOST + (q - 256)] = ldw(wp, q - 256, f32);
    } else if (q < WSF_N) {
      wsf[WSF_BPOST + (q - 1606)] = ldw(bp, q - 1606, f32);
    }
  }
}

// ---------------- one GEMM pass (conv or logits) ---------------------------
// H byte addr: px*2048 + chunk*512 + b*16  (chunk = s*2 + half)
// Wbuf (shorts): t*1024 + chunk*256 + b*8
// A/B frag (32x32x16): m|n = lane&31, k = half*8 + j
// C/D: col = lane&31, row = (reg&3) + 8*(reg>>2) + 4*half
__device__ __forceinline__ void gemm_pass(
    unsigned char* __restrict__ H, unsigned short* __restrict__ Wbuf,
    const uint4* __restrict__ gnext,   // next layer weights (global) or null
    const float* __restrict__ wsf, float* __restrict__ smb,
    int l, int nsteps, bool logits,
    int r, int b, int half, int tid) {
  f32x16 acc[5];
  {
    f32x4 bv[4];
    #pragma unroll
    for (int gq = 0; gq < 4; ++gq)
      bv[gq] = *(const f32x4*)(wsf + WSF_BALL + l * 32 + gq * 8 + half * 4);
    #pragma unroll
    for (int j = 0; j < 5; ++j)
      #pragma unroll
      for (int gq = 0; gq < 4; ++gq)
        #pragma unroll
        for (int q = 0; q < 4; ++q)
          acc[j][gq * 4 + q] = bv[gq][q];
  }

  #pragma unroll
  for (int dy = 0; dy < 3; ++dy) {
    const int ny = r + dy - 1;
    if ((unsigned)ny < 5u) {             // wave-uniform
      bf16x8 af[3][2];
      #pragma unroll
      for (int dx = 0; dx < 3; ++dx)
        #pragma unroll
        for (int s = 0; s < 2; ++s)
          if (s < nsteps)
            af[dx][s] = *(const bf16x8*)(Wbuf + (dy * 3 + dx) * 1024 + (s * 2 + half) * 256 + b * 8);
      #pragma unroll
      for (int nx = 0; nx < 5; ++nx) {
        const int q = ny * 5 + nx;
        #pragma unroll
        for (int s = 0; s < 2; ++s) {
          if (s < nsteps) {
            bf16x8 bf = *(const bf16x8*)(H + q * 2048 + (s * 2 + half) * 512 + b * 16);
            #pragma unroll
            for (int dx = 0; dx < 3; ++dx) {
              const int j = nx - dx + 1;  // output px consuming input nx via tap dx
              if (j >= 0 && j < 5)
                acc[j] = __builtin_amdgcn_mfma_f32_32x32x16_bf16(af[dx][s], bf, acc[j], 0, 0, 0);
            }
          }
        }
      }
    }
  }
  __syncthreads();   // all H + Wbuf reads complete

  if (!logits) {
    // prefetch next layer's weights first (latency covered by relu stores)
    uint4 wp0, wp1, wp2, wp3;
    const bool h3 = tid < 192;
    if (gnext) {
      wp0 = gnext[tid]; wp1 = gnext[tid + 320]; wp2 = gnext[tid + 640];
      if (h3) wp3 = gnext[tid + 960];
    }
    // relu + pack + in-place store (chunk gq, byte offset half*8)
    #pragma unroll
    for (int j = 0; j < 5; ++j) {
      unsigned char* base = H + (r * 5 + j) * 2048 + b * 16;
      #pragma unroll
      for (int gq = 0; gq < 3; ++gq) {
        uint2 sv;
        sv.x = pk2(fmaxf(acc[j][gq * 4 + 0], 0.f), fmaxf(acc[j][gq * 4 + 1], 0.f));
        sv.y = pk2(fmaxf(acc[j][gq * 4 + 2], 0.f), fmaxf(acc[j][gq * 4 + 3], 0.f));
        *(uint2*)(base + gq * 512 + half * 8) = sv;
      }
      if (half == 0)  // row 24 = reg 12 -> chunk 3, c0
        *(unsigned short*)(base + 3 * 512) = f2b(fmaxf(acc[j][12], 0.f));
    }
    if (gnext) {
      uint4* wb = (uint4*)Wbuf;
      wb[tid] = wp0; wb[tid + 320] = wp1; wb[tid + 640] = wp2;
      if (h3) wb[tid + 960] = wp3;
    }
  } else {
    // logits rows 0..5: half0 regs 0-3 = rows 0-3; rows 4,5 from half1 regs
    // 0,1 via shfl_xor(32). Softmax -> smb (overlays dead H).
    #pragma unroll
    for (int j = 0; j < 5; ++j) {
      const int px = r * 5 + j;
      float l4 = __shfl_xor(acc[j][0], 32);
      float l5 = __shfl_xor(acc[j][1], 32);
      if (half == 0) {
        float v0 = acc[j][0], v1 = acc[j][1], v2 = acc[j][2], v3 = acc[j][3];
        float m = fmaxf(fmaxf(fmaxf(v0, v1), fmaxf(v2, v3)), fmaxf(l4, l5));
        float e0 = __expf(v0 - m), e1 = __expf(v1 - m), e2 = __expf(v2 - m);
        float e3 = __expf(v3 - m), e4 = __expf(l4 - m), e5 = __expf(l5 - m);
        float inv = 1.f / (e0 + e1 + e2 + e3 + e4 + e5);
        float* sp = smb + (px * 32 + b) * 6;
        sp[0] = e0 * inv; sp[1] = e1 * inv; sp[2] = e2 * inv;
        sp[3] = e3 * inv; sp[4] = e4 * inv; sp[5] = e5 * inv;
      }
    }
  }
  __syncthreads();
}

// ---------------- main kernel ----------------------------------------------
__global__ __launch_bounds__(NTHR, 3) void pcnn_mfma(
    const void* __restrict__ inp,
    const void* __restrict__ w0raw,
    const unsigned short* __restrict__ wsb,
    const float* __restrict__ wsf,
    void* __restrict__ out) {
  __shared__ __align__(16) unsigned char H[25 * 2048];    // 51200 B
  __shared__ __align__(16) unsigned short Wbuf[9216];     // 18432 B
  __shared__ float colb[32 * 18];                         // 2304 B
  float* smb = (float*)H;                                 // [25][32][6] overlay

  const bool f32m = sniff_is_f32(w0raw);
  const int tid  = threadIdx.x;
  const int lane = tid & 63;
  const int r    = tid >> 6;        // wave = output row
  const int b    = lane & 31;       // patch col (n) / out-ch row (m)
  const int half = lane >> 5;
  const int g    = blockIdx.x;      // group of 32 patches

  // zero H (ch pads must stay zero through all layers)
  for (int i = tid; i < 12800; i += NTHR) ((unsigned int*)H)[i] = 0u;
  __syncthreads();
  // stage input [b][8c][25pix] -> H[pix][chunk0][b][c] ; copy layer-0 weights
  for (int e = tid; e < 6400; e += NTHR) {
    int pb = e / 200, rr = e % 200, c = rr / 25, pix = rr % 25;
    float v = ldw(inp, (long)g * 6400 + e, f32m);
    *(unsigned short*)(H + pix * 2048 + pb * 16 + c * 2) = f2b(v);
  }
  {
    const uint4* g4 = (const uint4*)wsb;
    uint4* wb = (uint4*)Wbuf;
    for (int i = tid; i < 1152; i += NTHR) wb[i] = g4[i];
  }
  __syncthreads();

  // ---- 7 relu conv layers + logits layer ----
  gemm_pass(H, Wbuf, (const uint4*)wsb + 1152, wsf, smb, 0, 1, false, r, b, half, tid);
  #pragma unroll 1
  for (int l = 1; l < 7; ++l)
    gemm_pass(H, Wbuf, (const uint4*)wsb + (l + 1) * 1152, wsf, smb, l, 2, false, r, b, half, tid);
  gemm_pass(H, Wbuf, nullptr, wsf, smb, 7, 2, true, r, b, half, tid);

  // ---- colors: 5x5 VALID conv on first 3 input channels (global re-read) ----
  for (int j = tid; j < 576; j += NTHR) {
    int pb = j / 18, oc = j % 18;
    const long ib = (long)g * 6400 + pb * 200;
    float s = wsf[WSF_BPOST + oc];
    #pragma unroll
    for (int ic = 0; ic < 3; ++ic)
      #pragma unroll
      for (int pix = 0; pix < 25; ++pix)
        s = fmaf(wsf[WSF_WPOST + (oc * 3 + ic) * 25 + pix],
                 ldw(inp, ib + ic * 25 + pix, f32m), s);
    colb[pb * 18 + oc] = s;
  }
  __syncthreads();

  // ---- mix + store: out[b][c][p] = sum_w colors[b][c*6+w] * sm[p][b][w] ----
  for (int e = tid; e < 2400; e += NTHR) {
    int pb = e / 75, rr = e % 75, c = rr / 25, p = rr % 25;
    float v = 0.f;
    #pragma unroll
    for (int w = 0; w < 6; ++w)
      v = fmaf(colb[pb * 18 + c * 6 + w], smb[(p * 32 + pb) * 6 + w], v);
    const long oidx = (long)g * 2400 + e;
    if (f32m) ((float*)out)[oidx] = v;
    else      ((unsigned short*)out)[oidx] = f2b(v);
  }
}

extern "C" void kernel_launch(void* const* d_in, const int* in_sizes, int n_in,
                              void* d_out, int out_size, void* d_ws, size_t ws_size,
                              hipStream_t stream) {
  unsigned short* wsb = (unsigned short*)d_ws;
  float* wsf = (float*)((char*)d_ws + WSF_BYTE);
  const int B = in_sizes[0] / 200;  // 32768

  const int prep_n = WSB_N + WSF_N;  // 75352
  prep_weights<<<(prep_n + 255) / 256, 256, 0, stream>>>(
      d_in[1], d_in[2], d_in[3], d_in[4], d_in[5], d_in[6], d_in[7], d_in[8],
      wsb, wsf);
  pcnn_mfma<<<B / 32, NTHR, 0, stream>>>(d_in[0], d_in[1], wsb, wsf, d_out);
}

// Round 8
// 236.575 us; speedup vs baseline: 1.5375x; 1.2048x over previous
//
#include <hip/hip_runtime.h>
#include <hip/hip_bf16.h>
#include <stdint.h>

// ---------------------------------------------------------------------------
// pcnn round 8: barrier-free, wave-private design.
//  - Block = 1 wave = 16 patches, private 31.5 KB LDS -> NO __syncthreads
//    anywhere; LDS RAW ordering within the wave is lgkmcnt (compiler).
//  - Per layer: load 25 pixel B-frags into VGPRs ONCE (ds_read_b128,
//    conflict-free), 18 A-frags from global (L2-hot), then 338 MFMAs
//    (valid taps only) over 50 independent acc chains. In-place H update
//    is safe: all B reads precede all H writes in program order.
//  - Logits: single M-tile; softmax in-register via shfl_xor(.,16); sm
//    overlays dead H. Colors from f32 in3 staged at input. Mix + store.
//  - 16x16x32 lane mapping identical to R4 (verified correct).
// ---------------------------------------------------------------------------

typedef short bf16x8 __attribute__((ext_vector_type(8)));
typedef float f32x4  __attribute__((ext_vector_type(4)));

// d_ws: WALL bf16 [8 layers][9 taps][32 o][32 c] @0 (73728 u16)
//   l=0: conv0 (c<8), l=1..6: mid, l=7: logits (o<6)
// f32 @ byte 147456: BALL[8][32] @0, WPOST[18][3][25] @256, BPOST[18] @1606
#define WSB_N     73728
#define WSF_BYTE  147456
#define WSF_BALL  0
#define WSF_WPOST 256
#define WSF_BPOST 1606
#define WSF_N     1624

__device__ __forceinline__ float b2f(unsigned short u) {
  union { unsigned int u; float f; } v; v.u = ((unsigned int)u) << 16; return v.f;
}
__device__ __forceinline__ unsigned short f2b(float f) {
  union { float f; unsigned int u; } v; v.f = f;
  unsigned int r = v.u + 0x7fffu + ((v.u >> 16) & 1u);  // RNE
  return (unsigned short)(r >> 16);
}
__device__ __forceinline__ unsigned int pk2(float lo, float hi) {
  __hip_bfloat162 h = __float22bfloat162_rn(make_float2(lo, hi));
  union { __hip_bfloat162 h; unsigned int u; } v; v.h = h; return v.u;
}
__device__ __forceinline__ bool sniff_is_f32(const void* w0raw) {
  const unsigned short* q = (const unsigned short*)w0raw;
  int hits = 0;
  #pragma unroll
  for (int i = 0; i < 64; ++i) {
    unsigned int e = (q[i] >> 7) & 0xFFu;
    if (e >= 130u) ++hits;
  }
  return hits > 0;
}
__device__ __forceinline__ float ldw(const void* p, long idx, bool f32) {
  return f32 ? ((const float*)p)[idx] : b2f(((const unsigned short*)p)[idx]);
}

// ---------------- weight pre-pack (R6-verified layout) ---------------------
__global__ void prep_weights(const void* __restrict__ w0,
                             const void* __restrict__ b0,
                             const void* __restrict__ wm,
                             const void* __restrict__ bm,
                             const void* __restrict__ wl,
                             const void* __restrict__ bl,
                             const void* __restrict__ wp,
                             const void* __restrict__ bp,
                             unsigned short* __restrict__ wsb,
                             float* __restrict__ wsf) {
  const bool f32 = sniff_is_f32(w0);
  int e = blockIdx.x * blockDim.x + threadIdx.x;
  if (e < WSB_N) {                        // WALL[l][t][o32][c32]
    int l = e / 9216, r = e % 9216, t = r / 1024, r2 = r % 1024;
    int o = r2 >> 5, c = r2 & 31;
    float v = 0.f;
    if (l == 0)     { if (o < 25 && c < 8)  v = ldw(w0, (o * 8 + c) * 9 + t, f32); }
    else if (l < 7) { if (o < 25 && c < 25) v = ldw(wm, (((l - 1) * 25 + o) * 25 + c) * 9 + t, f32); }
    else            { if (o < 6  && c < 25) v = ldw(wl, (o * 25 + c) * 9 + t, f32); }
    wsb[e] = f2b(v);
  } else {
    int q = e - WSB_N;
    if (q < 256) {                        // BALL[l][32]
      int l = q >> 5, row = q & 31;
      float v = 0.f;
      if (l == 0)     { if (row < 25) v = ldw(b0, row, f32); }
      else if (l < 7) { if (row < 25) v = ldw(bm, (l - 1) * 25 + row, f32); }
      else            { if (row < 6)  v = ldw(bl, row, f32); }
      wsf[WSF_BALL + q] = v;
    } else if (q < 256 + 1350) {
      wsf[WSF_WPOST + (q - 256)] = ldw(wp, q - 256, f32);
    } else if (q < WSF_N) {
      wsf[WSF_BPOST + (q - 1606)] = ldw(bp, q - 1606, f32);
    }
  }
}

// ---------------- main kernel: one wave per 16 patches ---------------------
__global__ __launch_bounds__(64, 2) void pcnn_mfma(
    const void* __restrict__ inp,
    const void* __restrict__ w0raw,
    const unsigned short* __restrict__ wsb,
    const float* __restrict__ wsf,
    void* __restrict__ out) {
  __shared__ __align__(16) unsigned short H[25 * 512];  // [px][b16][ch32] 25600 B
  __shared__ float in3[16 * 75];                        // [b][3c][25px] f32 4800 B
  __shared__ float colb[16 * 18];                       // colors 1152 B
  float* smb = (float*)H;  // [25px][16b][6] f32 overlay after logits (9600 B)

  const bool f32m = sniff_is_f32(w0raw);
  const int lane = threadIdx.x;         // 0..63
  const int col  = lane & 15;           // MFMA n (patch) / m (out ch)
  const int quad = lane >> 4;           // MFMA k-block / row-block
  const long g   = blockIdx.x;          // group of 16 patches

  // zero H (ch 8..31 pads must be 0 for the K=32 MFMA)
  #pragma unroll
  for (int i = 0; i < 25; ++i) {
    uint4 z; z.x = z.y = z.z = z.w = 0u;
    *(uint4*)((char*)H + (i * 64 + lane) * 16) = z;
  }
  // stage input [b][8c][25px] -> H[px][b][c] (bf16) + in3 (f32)
  for (int e = lane; e < 3200; e += 64) {
    int b = e / 200, r = e % 200, c = r / 25, px = r % 25;
    float v = ldw(inp, g * 3200 + e, f32m);
    H[px * 512 + b * 32 + c] = f2b(v);
    if (c < 3) in3[b * 75 + c * 25 + px] = v;
  }

  // ---- 7 relu conv layers (in-place H) ----
  #pragma unroll 1
  for (int l = 0; l < 7; ++l) {
    bf16x8 B[25];
    #pragma unroll
    for (int q = 0; q < 25; ++q)
      B[q] = *(const bf16x8*)(H + q * 512 + col * 32 + quad * 8);
    const unsigned short* WA = wsb + l * 9216;
    bf16x8 A0[9], A1[9];
    #pragma unroll
    for (int t = 0; t < 9; ++t) {
      A0[t] = *(const bf16x8*)(WA + t * 1024 + col * 32 + quad * 8);
      A1[t] = *(const bf16x8*)(WA + t * 1024 + (16 + col) * 32 + quad * 8);
    }
    const f32x4 bias0 = *(const f32x4*)(wsf + WSF_BALL + l * 32 + quad * 4);
    const f32x4 bias1 = *(const f32x4*)(wsf + WSF_BALL + l * 32 + 16 + quad * 4);

    #pragma unroll
    for (int p = 0; p < 25; ++p) {
      const int py = p / 5, pxx = p % 5;
      f32x4 a0 = bias0, a1 = bias1;
      #pragma unroll
      for (int dy = -1; dy <= 1; ++dy)
        #pragma unroll
        for (int dx = -1; dx <= 1; ++dx)
          if (py + dy >= 0 && py + dy < 5 && pxx + dx >= 0 && pxx + dx < 5) {
            const int t = (dy + 1) * 3 + (dx + 1);
            const int q = p + dy * 5 + dx;
            a0 = __builtin_amdgcn_mfma_f32_16x16x32_bf16(A0[t], B[q], a0, 0, 0, 0);
            a1 = __builtin_amdgcn_mfma_f32_16x16x32_bf16(A1[t], B[q], a1, 0, 0, 0);
          }
      // relu + pack + in-place store (R4-verified mapping)
      unsigned short* op = H + p * 512 + col * 32;
      uint2 s0;
      s0.x = pk2(fmaxf(a0[0], 0.f), fmaxf(a0[1], 0.f));
      s0.y = pk2(fmaxf(a0[2], 0.f), fmaxf(a0[3], 0.f));
      *(uint2*)(op + quad * 4) = s0;
      if (quad < 2) {
        uint2 s1;
        s1.x = pk2(fmaxf(a1[0], 0.f), fmaxf(a1[1], 0.f));
        s1.y = pk2(fmaxf(a1[2], 0.f), fmaxf(a1[3], 0.f));
        *(uint2*)(op + 16 + quad * 4) = s1;
      } else if (quad == 2) {  // ch 24
        op[24] = f2b(fmaxf(a1[0], 0.f));
      }
    }
  }

  // ---- logits layer (25 -> 6, no relu) + in-register softmax ----
  {
    bf16x8 B[25];
    #pragma unroll
    for (int q = 0; q < 25; ++q)
      B[q] = *(const bf16x8*)(H + q * 512 + col * 32 + quad * 8);
    const unsigned short* WA = wsb + 7 * 9216;
    bf16x8 A[9];
    #pragma unroll
    for (int t = 0; t < 9; ++t)
      A[t] = *(const bf16x8*)(WA + t * 1024 + col * 32 + quad * 8);
    const f32x4 biasl = *(const f32x4*)(wsf + WSF_BALL + 7 * 32 + quad * 4);

    #pragma unroll
    for (int p = 0; p < 25; ++p) {
      const int py = p / 5, pxx = p % 5;
      f32x4 a = biasl;
      #pragma unroll
      for (int dy = -1; dy <= 1; ++dy)
        #pragma unroll
        for (int dx = -1; dx <= 1; ++dx)
          if (py + dy >= 0 && py + dy < 5 && pxx + dx >= 0 && pxx + dx < 5) {
            const int t = (dy + 1) * 3 + (dx + 1);
            const int q = p + dy * 5 + dx;
            a = __builtin_amdgcn_mfma_f32_16x16x32_bf16(A[t], B[q], a, 0, 0, 0);
          }
      // rows: quad0 -> ch0-3; quad1 regs0,1 -> ch4,5
      float l4 = __shfl_xor(a[0], 16);
      float l5 = __shfl_xor(a[1], 16);
      if (quad == 0) {
        float m = fmaxf(fmaxf(fmaxf(a[0], a[1]), fmaxf(a[2], a[3])), fmaxf(l4, l5));
        float e0 = __expf(a[0] - m), e1 = __expf(a[1] - m), e2 = __expf(a[2] - m);
        float e3 = __expf(a[3] - m), e4 = __expf(l4 - m), e5 = __expf(l5 - m);
        float inv = 1.f / (e0 + e1 + e2 + e3 + e4 + e5);
        float* sp = smb + p * 96 + col * 6;   // overlay on dead H
        *(float2*)(sp + 0) = make_float2(e0 * inv, e1 * inv);
        *(float2*)(sp + 2) = make_float2(e2 * inv, e3 * inv);
        *(float2*)(sp + 4) = make_float2(e4 * inv, e5 * inv);
      }
    }
  }

  // ---- colors: 5x5 VALID conv on first 3 input channels (f32, from in3) ----
  for (int j = lane; j < 288; j += 64) {
    int b = j / 18, oc = j % 18;
    float s = wsf[WSF_BPOST + oc];
    #pragma unroll
    for (int ic = 0; ic < 3; ++ic)
      #pragma unroll
      for (int px = 0; px < 25; ++px)
        s = fmaf(wsf[WSF_WPOST + (oc * 3 + ic) * 25 + px], in3[b * 75 + ic * 25 + px], s);
    colb[b * 18 + oc] = s;
  }

  // ---- mix + store: out[b][c][p] = sum_w colors[b][c*6+w] * sm[p][b][w] ----
  for (int e = lane; e < 1200; e += 64) {
    int b = e / 75, r = e % 75, c = r / 25, p = r % 25;
    float v = 0.f;
    #pragma unroll
    for (int w = 0; w < 6; ++w)
      v = fmaf(colb[b * 18 + c * 6 + w], smb[p * 96 + b * 6 + w], v);
    const long oidx = g * 1200 + e;
    if (f32m) ((float*)out)[oidx] = v;
    else      ((unsigned short*)out)[oidx] = f2b(v);
  }
}

extern "C" void kernel_launch(void* const* d_in, const int* in_sizes, int n_in,
                              void* d_out, int out_size, void* d_ws, size_t ws_size,
                              hipStream_t stream) {
  unsigned short* wsb = (unsigned short*)d_ws;
  float* wsf = (float*)((char*)d_ws + WSF_BYTE);
  const int B = in_sizes[0] / 200;  // 32768

  const int prep_n = WSB_N + WSF_N;  // 75352
  prep_weights<<<(prep_n + 255) / 256, 256, 0, stream>>>(
      d_in[1], d_in[2], d_in[3], d_in[4], d_in[5], d_in[6], d_in[7], d_in[8],
      wsb, wsf);
  pcnn_mfma<<<B / 16, 64, 0, stream>>>(d_in[0], d_in[1], wsb, wsf, d_out);
}